// Round 1
// baseline (700.473 us; speedup 1.0000x reference)
//
#include <hip/hip_runtime.h>
#include <math.h>

// Problem constants (setup_inputs: N=32, C=1, W=512, L=512)
#define WD 512          // image / detector width
#define PF 1024         // FFT pad length
#define LH2 1028        // shifted ramp-kernel table length
#define HSW 1160        // swizzled h2 LDS size (max hsw(1023)=1150)

// Workspace layout (float offsets). ws bytes: 16 KB + 33.55 MB table.
#define OFF_H2 0        // 1028 floats
#define OFF_ANG 2048    // 512 x float4 (chw, shw, wB, iA-bits)
#define OFF_PK 4096     // packed fp16 sinogram: [g][l][s] uint4 (4 imgs x (y[s],y[s+1]))

#define GOFF 107        // LDS slot = detector_index + GOFF (guards absorb out-of-circle idx)
#define GSLOTS 726      // covers idx in [-107, 618]

typedef __fp16 half2_t __attribute__((ext_vector_type(2)));

__device__ __forceinline__ half2_t pkh(float a, float b) {
  return __builtin_amdgcn_cvt_pkrtz(a, b);   // v_cvt_pkrtz_f16_f32
}
__device__ __forceinline__ unsigned pkbits(float a, float b) {
  return __builtin_bit_cast(unsigned, pkh(a, b));
}
__device__ __forceinline__ float dot2f(unsigned tapbits, half2_t w, float c) {
  half2_t tp = __builtin_bit_cast(half2_t, tapbits);
  return __builtin_amdgcn_fdot2(tp, w, c, false);   // v_dot2_f32_f16
}
// Bank swizzle: stride-16-float lanes -> stride 18 mod 32 (2-way = free).
__device__ __forceinline__ int hsw(int i) { return i + (i >> 3); }

__device__ __forceinline__ float t2(int p) {
  return (float)(-1.0 + 2.0 * (double)p / (double)(WD - 1));
}

// ---------------------------------------------------------------------------
// Setup: h2[i] = h[(i-512) & 1023] via v_cos (arg in REVOLUTIONS).
// ---------------------------------------------------------------------------
__global__ void setup_kernel(const float* __restrict__ theta,
                             float* __restrict__ ws, int L) {
  int gid = blockIdx.x * blockDim.x + threadIdx.x;
  if (gid < LH2) {
    int dd = gid - (PF / 2);
    if (dd < 0) dd = -dd;
    float acc = 0.f;
    for (int k = 0; k < PF; ++k) {
      int kk = (k <= PF / 2) ? k : (PF - k);
      float filt = 2.f * (float)kk * (1.f / (float)PF);
      int m = (k * dd) & (PF - 1);            // phase in [0,1) revolutions
#if __has_builtin(__builtin_amdgcn_cosf)
      float cv = __builtin_amdgcn_cosf((float)m * (1.f / (float)PF));
#else
      float cv = cosf((float)m * (6.28318530717958647692f / (float)PF));
#endif
      acc = fmaf(filt, cv, acc);
    }
    ws[OFF_H2 + gid] = acc * (1.f / (float)PF);
  } else if (gid < LH2 + L) {
    int l = gid - LH2;
    double rad = (double)theta[l] * 0.017453292519943295;
    const float hw = 0.5f * (float)(WD - 1);
    float cx = (float)l * (float)((double)(WD - 1) / (double)(L - 1));
    float c0 = floorf(cx);
    float wc = cx - c0;
    int ia = (int)c0;
    float ok = (ia + 1 <= WD - 1) ? 1.f : 0.f;
    float4 a;
    a.x = (float)cos(rad) * hw;
    a.y = (float)sin(rad) * hw;
    a.z = wc * ok;                       // wB (0 when L==WD)
    a.w = __int_as_float(ia);
    ((float4*)(ws + OFF_ANG))[l] = a;
  }
}

// ---------------------------------------------------------------------------
// Ramp filter -> packed fp16 table. 256-thread block, tile 16 l x 512 r,
// 2x16 microtile, 4 blocks/CU (4 waves/SIMD). Loads batched per 8-m chunk
// so the rolling h-window never serializes on lgkmcnt.
// ---------------------------------------------------------------------------
__global__ __launch_bounds__(256, 4) void filter_kernel(
    const float* __restrict__ x, const float* __restrict__ ws,
    unsigned char* __restrict__ pk) {
  __shared__ float h2l[HSW];
  __shared__ __align__(16) float bxl[64][20];   // [m][l], 16 l + 4 pad
  const int t = threadIdx.x;
  const int tx = t & 31, ty = t >> 5;          // tx: r/16 (0..31), ty: l/2 (0..7)
  const int n = blockIdx.y;
  const int g = n >> 2, k = n & 3;
  const int l0 = blockIdx.x << 4;

  for (int i = t; i < LH2; i += 256) h2l[hsw(i)] = ws[OFF_H2 + i];

  float acc[2][16] = {};
  const float* __restrict__ xn = x + (size_t)n * WD * WD;
  const int first = tx << 4;

  for (int mc = 0; mc < WD; mc += 64) {
    __syncthreads();
    {                                          // stage x[mc..mc+63][l0..l0+15]
      int row = t >> 2;
      int c4 = (t & 3) << 2;
      float4 v = *(const float4*)(xn + (size_t)(mc + row) * WD + l0 + c4);
      *(float4*)(&bxl[row][c4]) = v;
    }
    __syncthreads();
    const int rbase = first + 512 - mc;
    float w[16];
#pragma unroll
    for (int j = 0; j < 16; ++j) w[j] = h2l[hsw(rbase + j)];
    for (int mb = 0; mb < 64; mb += 8) {
      float nh8[8];
      float2 bv8[8];
#pragma unroll
      for (int kk = 0; kk < 8; ++kk) {         // batch LDS loads (8 indep each)
        nh8[kk] = h2l[hsw(rbase - (mb + kk) - 1)];
        bv8[kk] = *(const float2*)(&bxl[mb + kk][ty << 1]);
      }
#pragma unroll
      for (int kk = 0; kk < 8; ++kk) {
        float b0 = bv8[kk].x, b1 = bv8[kk].y;
#pragma unroll
        for (int rj = 0; rj < 16; ++rj) {
          acc[0][rj] = fmaf(b0, w[rj], acc[0][rj]);
          acc[1][rj] = fmaf(b1, w[rj], acc[1][rj]);
        }
#pragma unroll
        for (int j = 15; j > 0; --j) w[j] = w[j - 1];   // renamed by unroll
        w[0] = nh8[kk];
      }
    }
  }

  // Epilogue: scatter into interleaved pk table (byte lane k, group g).
#pragma unroll
  for (int li = 0; li < 2; ++li) {
    int l = l0 + (ty << 1) + li;
    size_t rowb = ((size_t)(g * 512 + l) * 512) * 16 + (size_t)(k << 2);
#pragma unroll
    for (int j = 0; j < 15; ++j) {             // full entries s = first..first+14
      unsigned d = pkbits(acc[li][j], acc[li][j + 1]);
      *(unsigned*)(pk + rowb + (size_t)(first + j) * 16) = d;
    }
    unsigned lastp = pkbits(acc[li][15], 0.f);
    if (first + 15 == 511) {
      *(unsigned*)(pk + rowb + (size_t)511 * 16) = lastp;     // hi half must be 0
    } else {
      *(unsigned short*)(pk + rowb + (size_t)(first + 15) * 16) = (unsigned short)lastp;
    }
    if (first > 0) {                            // hi half of entry s = first-1
      unsigned fh = pkbits(acc[li][0], 0.f);
      *(unsigned short*)(pk + rowb + (size_t)(first - 1) * 16 + 2) = (unsigned short)fh;
    }
  }
}

// ---------------------------------------------------------------------------
// Backprojection v7: v6 structure (1024 threads, 64x64 px x 4 imgs, 2 angles
// per LDS round, ONE barrier per 2 angles) + LDS/L1 pipe split: 6 of 8
// dj-gathers per round stay on the LDS pipe (saturated at ~12cy/ds_read_b128),
// 2 of 8 (angle B, dj 2..3) go to vector-memory gathers from the L1-resident
// 8KB pk row. Gathers are issued BEFORE the barrier (no LDS dependence) and
// consumed after the LDS accumulates, hiding L1 latency under ~150 instrs.
// In-circle pixels provably have idx in [0,511]; out-of-circle results are
// masked at the end, so a clamp (not LDS guards) suffices on the global path.
// ---------------------------------------------------------------------------
__device__ __forceinline__ uint4 blend4(uint4 a, uint4 b, float wA, float wB) {
  unsigned r[4];
  const unsigned* pa = &a.x; const unsigned* pb = &b.x;
#pragma unroll
  for (int i = 0; i < 4; ++i) {
    half2_t ha = __builtin_bit_cast(half2_t, pa[i]);
    half2_t hb = __builtin_bit_cast(half2_t, pb[i]);
    r[i] = pkbits(fmaf((float)ha.x, wA, (float)hb.x * wB),
                  fmaf((float)ha.y, wA, (float)hb.y * wB));
  }
  return make_uint4(r[0], r[1], r[2], r[3]);
}

__device__ __forceinline__ void loadrow(const unsigned char* gb, float4 a, int s,
                                        uint4& v) {
  int ia = __float_as_int(a.w);
  v = *(const uint4*)(gb + (size_t)ia * (512 * 16) + (size_t)s * 16);
  float wB = a.z;
  if (wB != 0.f) {                       // generic angle interp (never taken, L==WD)
    int ib = ia + 1 < 511 ? ia + 1 : 511;
    uint4 u = *(const uint4*)(gb + (size_t)ib * (512 * 16) + (size_t)s * 16);
    v = blend4(v, u, 1.f - wB, wB);
  }
}

template <int D0, int D1>
__device__ __forceinline__ void accum_angle_part(const uint4* __restrict__ br,
                                                 float4 a, float tiv,
                                                 const float* __restrict__ tjv,
                                                 float hw, float acc[4][4]) {
  const float chw = a.x, shw = a.y;
  float bi = fmaf(tiv, -shw, hw);
#pragma unroll
  for (int dj = D0; dj < D1; ++dj) {
    float ry = fmaf(tjv[dj], chw, bi);
    int idx = (int)ry;                   // trunc; OOB lands in zero guards
    float w1 = ry - (float)idx;
    half2_t wpk = pkh(1.f - w1, w1);
    uint4 q = br[idx + GOFF];            // one ds_read_b128 serves 4 images
    acc[dj][0] = dot2f(q.x, wpk, acc[dj][0]);
    acc[dj][1] = dot2f(q.y, wpk, acc[dj][1]);
    acc[dj][2] = dot2f(q.z, wpk, acc[dj][2]);
    acc[dj][3] = dot2f(q.w, wpk, acc[dj][3]);
  }
}

__global__ __launch_bounds__(1024, 8) void backproj_kernel(
    const float* __restrict__ ws, const unsigned char* __restrict__ pk,
    float* __restrict__ out, int L) {
  __shared__ __align__(16) uint4 buf[2][2][GSLOTS];   // [round parity][angle][slot]
  const int t = threadIdx.x;
  const int tx = t & 15, ty = t >> 4;        // ty: 0..63 (full i of tile)
  const int j0 = (blockIdx.x & 7) << 6;
  const int i0 = (blockIdx.x >> 3) << 6;
  const int g = blockIdx.y;
  const int n0 = g << 2;

  const float tiv = t2(i0 + ty);
  float tjv[4];
#pragma unroll
  for (int a = 0; a < 4; ++a) tjv[a] = t2(j0 + tx + 16 * a);

  // Corner-tile skip: entire 64x64 tile outside the circle -> zeros, no compute.
  {
    float il = t2(i0), ih = t2(i0 + 63);
    float jl = t2(j0), jh = t2(j0 + 63);
    float mi = (il <= 0.f && ih >= 0.f) ? 0.f : fminf(fabsf(il), fabsf(ih));
    float mj = (jl <= 0.f && jh >= 0.f) ? 0.f : fminf(fabsf(jl), fabsf(jh));
    if (mi * mi + mj * mj > 1.f) {
#pragma unroll
      for (int k = 0; k < 4; ++k) {
        float* ob = out + (size_t)(n0 + k) * WD * WD + (size_t)(i0 + ty) * WD;
#pragma unroll
        for (int dj = 0; dj < 4; ++dj) ob[j0 + tx + 16 * dj] = 0.f;
      }
      return;
    }
  }

  const float4* __restrict__ angp = (const float4*)(ws + OFF_ANG);
  const unsigned char* gb = pk + (size_t)g * (512 * 512 * 16);

  for (int s = t; s < 2 * 2 * GSLOTS; s += 1024)
    ((uint4*)buf)[s] = make_uint4(0u, 0u, 0u, 0u);
  __syncthreads();                       // guards visible before first staging

  const float hw = 0.5f * (float)(WD - 1);
  float acc[4][4] = {};                  // [dj][img]

  const int sA = t & 511;                // staged slot
  const int p = t >> 9;                  // which of the round's 2 angles we stage

  float4 aA = angp[0];
  float4 aB = angp[L > 1 ? 1 : 0];
  uint4 v;
  loadrow(gb, p ? aB : aA, sA, v);

  const int rounds = (L + 1) >> 1;
  for (int r = 0; r < rounds; ++r) {
    const int rp = r & 1;

    // ---- angle B, dj 2..3 via vector-memory (L1-resident row gather) ----
    uint4 qg[2]; half2_t wg[2]; int idxc[2];
    const bool haveB = (2 * r + 1 < L);
    if (haveB) {
      const unsigned char* rowB =
          gb + (size_t)__float_as_int(aB.w) * (512 * 16);
      float biB = fmaf(tiv, -aB.y, hw);
#pragma unroll
      for (int u = 0; u < 2; ++u) {
        float ry = fmaf(tjv[2 + u], aB.x, biB);
        int id0 = (int)ry;               // trunc (in-circle: == floor, >= 0)
        float w1 = ry - (float)id0;
        int ic = id0 < 0 ? 0 : (id0 > 511 ? 511 : id0);   // OOB masked later
        idxc[u] = ic;
        wg[u] = pkh(1.f - w1, w1);
        qg[u] = *(const uint4*)(rowB + (size_t)ic * 16);
      }
      if (aB.z != 0.f) {                 // generic angle interp (never taken)
        int ia2 = __float_as_int(aB.w) + 1;
        ia2 = ia2 < 511 ? ia2 : 511;
        const unsigned char* rowB2 = gb + (size_t)ia2 * (512 * 16);
#pragma unroll
        for (int u = 0; u < 2; ++u) {
          uint4 q2 = *(const uint4*)(rowB2 + (size_t)idxc[u] * 16);
          qg[u] = blend4(qg[u], q2, 1.f - aB.z, aB.z);
        }
      }
    }

    buf[rp][p][GOFF + sA] = v;           // 1 ds_write_b128, conflict-free
    int na = 2 * r + 2, nb = 2 * r + 3;
    float4 aA2 = angp[na < L ? na : L - 1];
    float4 aB2 = angp[nb < L ? nb : L - 1];
    if (r + 1 < rounds) loadrow(gb, p ? aB2 : aA2, sA, v);   // overlap compute
    __syncthreads();                     // ONE barrier per 2 angles

    accum_angle_part<0, 4>(&buf[rp][0][0], aA, tiv, tjv, hw, acc);
    if (haveB) {
      accum_angle_part<0, 2>(&buf[rp][1][0], aB, tiv, tjv, hw, acc);
      // consume the global gathers (latency hidden by the LDS accums above)
#pragma unroll
      for (int u = 0; u < 2; ++u) {
        acc[2 + u][0] = dot2f(qg[u].x, wg[u], acc[2 + u][0]);
        acc[2 + u][1] = dot2f(qg[u].y, wg[u], acc[2 + u][1]);
        acc[2 + u][2] = dot2f(qg[u].z, wg[u], acc[2 + u][2]);
        acc[2 + u][3] = dot2f(qg[u].w, wg[u], acc[2 + u][3]);
      }
    }
    aA = aA2; aB = aB2;
  }

  const float scale = (float)(3.14159265358979323846 / (2.0 * (double)L));
#pragma unroll
  for (int k = 0; k < 4; ++k) {
    float* ob = out + (size_t)(n0 + k) * WD * WD + (size_t)(i0 + ty) * WD;
#pragma unroll
    for (int dj = 0; dj < 4; ++dj) {
      float rr = tiv * tiv + tjv[dj] * tjv[dj];
      ob[j0 + tx + 16 * dj] = (rr <= 1.f) ? acc[dj][k] * scale : 0.f;
    }
  }
}

extern "C" void kernel_launch(void* const* d_in, const int* in_sizes, int n_in,
                              void* d_out, int out_size, void* d_ws, size_t ws_size,
                              hipStream_t stream) {
  const float* x = (const float*)d_in[0];
  const float* theta = (const float*)d_in[1];
  float* out = (float*)d_out;
  float* ws = (float*)d_ws;
  int L = in_sizes[1];                       // 512
  int NC = in_sizes[0] / (WD * WD);          // 32
  unsigned char* pk = (unsigned char*)(ws + OFF_PK);

  int nset = LH2 + L;
  hipLaunchKernelGGL(setup_kernel, dim3((nset + 255) / 256), dim3(256), 0, stream,
                     theta, ws, L);
  hipLaunchKernelGGL(filter_kernel, dim3(32, NC), dim3(256), 0, stream,
                     x, ws, pk);
  hipLaunchKernelGGL(backproj_kernel, dim3(64, NC / 4), dim3(1024), 0, stream,
                     ws, pk, out, L);
}

// Round 2
// 555.364 us; speedup vs baseline: 1.2613x; 1.2613x over previous
//
#include <hip/hip_runtime.h>
#include <math.h>

// Problem constants (setup_inputs: N=32, C=1, W=512, L=512)
#define WD 512          // image / detector width
#define PF 1024         // FFT pad length
#define LH2 1028        // shifted ramp-kernel table length

// Workspace layout (float offsets). ws bytes: 16 KB + 33.55 MB table.
#define OFF_H2 0        // 1028 floats
#define OFF_ANG 2048    // 512 x float4 (chw, shw, wB, iA-bits)
#define OFF_PK 4096     // packed fp16 sinogram: [g][l][s] uint4 (4 imgs x (y[s],y[s+1]))

#define GOFF 107        // LDS slot = detector_index + GOFF (guards absorb out-of-circle idx)
#define GSLOTS 726      // covers idx in [-107, 618]

typedef __fp16 half2_t __attribute__((ext_vector_type(2)));

__device__ __forceinline__ half2_t pkh(float a, float b) {
  return __builtin_amdgcn_cvt_pkrtz(a, b);   // v_cvt_pkrtz_f16_f32
}
__device__ __forceinline__ unsigned pkbits(float a, float b) {
  return __builtin_bit_cast(unsigned, pkh(a, b));
}
__device__ __forceinline__ float dot2f(unsigned tapbits, half2_t w, float c) {
  half2_t tp = __builtin_bit_cast(half2_t, tapbits);
  return __builtin_amdgcn_fdot2(tp, w, c, false);   // v_dot2_f32_f16
}
// Bank swizzle: stride-8/16-float lanes -> stride 9/18 mod 32 (<=2-way = free).
__device__ __forceinline__ int hsw(int i) { return i + (i >> 3); }

__device__ __forceinline__ float t2(int p) {
  return (float)(-1.0 + 2.0 * (double)p / (double)(WD - 1));
}

// ---------------------------------------------------------------------------
// Setup: h2[i] = h[(i-512) & 1023] via v_cos (arg in REVOLUTIONS).
// NOTE (round 2): h has EXACT zeros at all even offsets d != 0 (triangle
// spectrum 2|f| frequency-sampled with even P). filter_kernel now consumes
// only the odd taps + the d=0 center tap; this table stays full-length so
// the compressed view h2[2t+1] / h2[512] can be loaded from it.
// ---------------------------------------------------------------------------
__global__ void setup_kernel(const float* __restrict__ theta,
                             float* __restrict__ ws, int L) {
  int gid = blockIdx.x * blockDim.x + threadIdx.x;
  if (gid < LH2) {
    int dd = gid - (PF / 2);
    if (dd < 0) dd = -dd;
    float acc = 0.f;
    for (int k = 0; k < PF; ++k) {
      int kk = (k <= PF / 2) ? k : (PF - k);
      float filt = 2.f * (float)kk * (1.f / (float)PF);
      int m = (k * dd) & (PF - 1);            // phase in [0,1) revolutions
#if __has_builtin(__builtin_amdgcn_cosf)
      float cv = __builtin_amdgcn_cosf((float)m * (1.f / (float)PF));
#else
      float cv = cosf((float)m * (6.28318530717958647692f / (float)PF));
#endif
      acc = fmaf(filt, cv, acc);
    }
    ws[OFF_H2 + gid] = acc * (1.f / (float)PF);
  } else if (gid < LH2 + L) {
    int l = gid - LH2;
    double rad = (double)theta[l] * 0.017453292519943295;
    const float hw = 0.5f * (float)(WD - 1);
    float cx = (float)l * (float)((double)(WD - 1) / (double)(L - 1));
    float c0 = floorf(cx);
    float wc = cx - c0;
    int ia = (int)c0;
    float ok = (ia + 1 <= WD - 1) ? 1.f : 0.f;
    float4 a;
    a.x = (float)cos(rad) * hw;
    a.y = (float)sin(rad) * hw;
    a.z = wc * ok;                       // wB (0 when L==WD)
    a.w = __int_as_float(ia);
    ((float4*)(ws + OFF_ANG))[l] = a;
  }
}

// ---------------------------------------------------------------------------
// Ramp filter -> packed fp16 table. v2: odd-taps-only convolution.
// The frequency-sampled ramp has h[d] == 0 for even d != 0 (exact), so
// out[s] = h0*x[s] + sum_{odd d} h[d]*x[s-d]. Process m in PAIRS with a
// 9-wide rolling window over the compressed odd-tap table ho[t] = h2[2t+1]:
//   pair a, m=2a   (even): updates odd  j via w[1..8]   (taps ho[tb-a+b])
//   pair a, m=2a+1 (odd) : updates even j via w[0..7]   (taps ho[tb-a-1+b])
// then one shift. FMAs per thread: 16384 -> 8192. Center tap added from the
// staged chunk containing the thread's own rows. 256 threads, 16 l x 512 r,
// 2x16 microtile, 4 blocks/CU.
// ---------------------------------------------------------------------------
__global__ __launch_bounds__(256, 4) void filter_kernel(
    const float* __restrict__ x, const float* __restrict__ ws,
    unsigned char* __restrict__ pk) {
  __shared__ float hol[584];                    // odd taps, swizzled, +2 front guard
  __shared__ __align__(16) float bxl[64][20];   // [m][l], 16 l + 4 pad
  const int t = threadIdx.x;
  const int tx = t & 31, ty = t >> 5;          // tx: r/16 (0..31), ty: l/2 (0..7)
  const int n = blockIdx.y;
  const int g = n >> 2, k = n & 3;
  const int l0 = blockIdx.x << 4;

  for (int i = t; i < 512; i += 256) hol[2 + hsw(i)] = ws[OFF_H2 + 2 * i + 1];
  const float h0 = ws[OFF_H2 + 512];           // center tap (broadcast load)

  float acc[2][16] = {};
  const float* __restrict__ xn = x + (size_t)n * WD * WD;
  const int first = tx << 4;
  const int cchunk = first & ~63;              // chunk holding rows first..first+15

  for (int mc = 0; mc < WD; mc += 64) {
    __syncthreads();
    {                                          // stage x[mc..mc+63][l0..l0+15]
      int row = t >> 2;
      int c4 = (t & 3) << 2;
      float4 v = *(const float4*)(xn + (size_t)(mc + row) * WD + l0 + c4);
      *(float4*)(&bxl[row][c4]) = v;
    }
    __syncthreads();
    const int tb = (first + 512 - mc) >> 1;    // rbase/2 (rbase always even)
    float w[9];
#pragma unroll
    for (int j = 0; j < 9; ++j) w[j] = hol[2 + hsw(tb - 1 + j)];
    if (mc == cchunk) {                        // center tap h0 * x[s]
      const int rloc = first & 63;
#pragma unroll
      for (int j = 0; j < 16; ++j) {
        float2 cv = *(const float2*)(&bxl[rloc + j][ty << 1]);
        acc[0][j] = fmaf(h0, cv.x, acc[0][j]);
        acc[1][j] = fmaf(h0, cv.y, acc[1][j]);
      }
    }
    for (int mb = 0; mb < 64; mb += 8) {       // 4 m-pairs per batch
      float nh4[4];
      float2 bv8[8];
#pragma unroll
      for (int kk = 0; kk < 8; ++kk)           // batch LDS loads (indep)
        bv8[kk] = *(const float2*)(&bxl[mb + kk][ty << 1]);
#pragma unroll
      for (int kk = 0; kk < 4; ++kk)
        nh4[kk] = hol[2 + hsw(tb - (mb >> 1) - kk - 2)];  // hsw(-1)+2 == 0: safe
#pragma unroll
      for (int kk = 0; kk < 4; ++kk) {
        float2 xe = bv8[2 * kk], xo = bv8[2 * kk + 1];
#pragma unroll
        for (int b = 0; b < 8; ++b) {
          acc[0][2 * b + 1] = fmaf(xe.x, w[b + 1], acc[0][2 * b + 1]);
          acc[1][2 * b + 1] = fmaf(xe.y, w[b + 1], acc[1][2 * b + 1]);
          acc[0][2 * b]     = fmaf(xo.x, w[b],     acc[0][2 * b]);
          acc[1][2 * b]     = fmaf(xo.y, w[b],     acc[1][2 * b]);
        }
#pragma unroll
        for (int j = 8; j > 0; --j) w[j] = w[j - 1];   // renamed by unroll
        w[0] = nh4[kk];
      }
    }
  }

  // Epilogue: scatter into interleaved pk table (byte lane k, group g).
#pragma unroll
  for (int li = 0; li < 2; ++li) {
    int l = l0 + (ty << 1) + li;
    size_t rowb = ((size_t)(g * 512 + l) * 512) * 16 + (size_t)(k << 2);
#pragma unroll
    for (int j = 0; j < 15; ++j) {             // full entries s = first..first+14
      unsigned d = pkbits(acc[li][j], acc[li][j + 1]);
      *(unsigned*)(pk + rowb + (size_t)(first + j) * 16) = d;
    }
    unsigned lastp = pkbits(acc[li][15], 0.f);
    if (first + 15 == 511) {
      *(unsigned*)(pk + rowb + (size_t)511 * 16) = lastp;     // hi half must be 0
    } else {
      *(unsigned short*)(pk + rowb + (size_t)(first + 15) * 16) = (unsigned short)lastp;
    }
    if (first > 0) {                            // hi half of entry s = first-1
      unsigned fh = pkbits(acc[li][0], 0.f);
      *(unsigned short*)(pk + rowb + (size_t)(first - 1) * 16 + 2) = (unsigned short)fh;
    }
  }
}

// ---------------------------------------------------------------------------
// Backprojection v6 (REVERTED from v7): 1024-thread blocks (32 waves/CU),
// 64x64 px x 4 imgs, TWO angles per LDS round (4 buffers), ONE barrier per
// 2 angles. Thread: 1 i-row x 4 j. Corner tiles fully outside the circle
// skip all compute. Staging: 1 uint4 load + 1 ds_write_b128/thread.
// v7 post-mortem: routing 2/8 gathers to vector-memory cost ~26 cy/gather
// (TCP is cache-line-serial on scattered lanes) vs 12 cy ds_read_b128 — LDS
// is the only high-throughput gather engine on CDNA4. Do not re-try.
// ---------------------------------------------------------------------------
__device__ __forceinline__ uint4 blend4(uint4 a, uint4 b, float wA, float wB) {
  unsigned r[4];
  const unsigned* pa = &a.x; const unsigned* pb = &b.x;
#pragma unroll
  for (int i = 0; i < 4; ++i) {
    half2_t ha = __builtin_bit_cast(half2_t, pa[i]);
    half2_t hb = __builtin_bit_cast(half2_t, pb[i]);
    r[i] = pkbits(fmaf((float)ha.x, wA, (float)hb.x * wB),
                  fmaf((float)ha.y, wA, (float)hb.y * wB));
  }
  return make_uint4(r[0], r[1], r[2], r[3]);
}

__device__ __forceinline__ void loadrow(const unsigned char* gb, float4 a, int s,
                                        uint4& v) {
  int ia = __float_as_int(a.w);
  v = *(const uint4*)(gb + (size_t)ia * (512 * 16) + (size_t)s * 16);
  float wB = a.z;
  if (wB != 0.f) {                       // generic angle interp (never taken, L==WD)
    int ib = ia + 1 < 511 ? ia + 1 : 511;
    uint4 u = *(const uint4*)(gb + (size_t)ib * (512 * 16) + (size_t)s * 16);
    v = blend4(v, u, 1.f - wB, wB);
  }
}

__device__ __forceinline__ void accum_angle(const uint4* __restrict__ br,
                                            float4 a, float tiv,
                                            const float* __restrict__ tjv,
                                            float hw, float acc[4][4]) {
  const float chw = a.x, shw = a.y;
  float bi = fmaf(tiv, -shw, hw);
#pragma unroll
  for (int dj = 0; dj < 4; ++dj) {
    float ry = fmaf(tjv[dj], chw, bi);
    int idx = (int)ry;                   // trunc; OOB lands in zero guards
    float w1 = ry - (float)idx;
    half2_t wpk = pkh(1.f - w1, w1);
    uint4 q = br[idx + GOFF];            // one ds_read_b128 serves 4 images
    acc[dj][0] = dot2f(q.x, wpk, acc[dj][0]);
    acc[dj][1] = dot2f(q.y, wpk, acc[dj][1]);
    acc[dj][2] = dot2f(q.z, wpk, acc[dj][2]);
    acc[dj][3] = dot2f(q.w, wpk, acc[dj][3]);
  }
}

__global__ __launch_bounds__(1024, 8) void backproj_kernel(
    const float* __restrict__ ws, const unsigned char* __restrict__ pk,
    float* __restrict__ out, int L) {
  __shared__ __align__(16) uint4 buf[2][2][GSLOTS];   // [round parity][angle][slot]
  const int t = threadIdx.x;
  const int tx = t & 15, ty = t >> 4;        // ty: 0..63 (full i of tile)
  const int j0 = (blockIdx.x & 7) << 6;
  const int i0 = (blockIdx.x >> 3) << 6;
  const int g = blockIdx.y;
  const int n0 = g << 2;

  const float tiv = t2(i0 + ty);
  float tjv[4];
#pragma unroll
  for (int a = 0; a < 4; ++a) tjv[a] = t2(j0 + tx + 16 * a);

  // Corner-tile skip: entire 64x64 tile outside the circle -> zeros, no compute.
  {
    float il = t2(i0), ih = t2(i0 + 63);
    float jl = t2(j0), jh = t2(j0 + 63);
    float mi = (il <= 0.f && ih >= 0.f) ? 0.f : fminf(fabsf(il), fabsf(ih));
    float mj = (jl <= 0.f && jh >= 0.f) ? 0.f : fminf(fabsf(jl), fabsf(jh));
    if (mi * mi + mj * mj > 1.f) {
#pragma unroll
      for (int k = 0; k < 4; ++k) {
        float* ob = out + (size_t)(n0 + k) * WD * WD + (size_t)(i0 + ty) * WD;
#pragma unroll
        for (int dj = 0; dj < 4; ++dj) ob[j0 + tx + 16 * dj] = 0.f;
      }
      return;
    }
  }

  const float4* __restrict__ angp = (const float4*)(ws + OFF_ANG);
  const unsigned char* gb = pk + (size_t)g * (512 * 512 * 16);

  for (int s = t; s < 2 * 2 * GSLOTS; s += 1024)
    ((uint4*)buf)[s] = make_uint4(0u, 0u, 0u, 0u);
  __syncthreads();                       // guards visible before first staging

  const float hw = 0.5f * (float)(WD - 1);
  float acc[4][4] = {};                  // [dj][img]

  const int sA = t & 511;                // staged slot
  const int p = t >> 9;                  // which of the round's 2 angles we stage

  float4 aA = angp[0];
  float4 aB = angp[L > 1 ? 1 : 0];
  uint4 v;
  loadrow(gb, p ? aB : aA, sA, v);

  const int rounds = (L + 1) >> 1;
  for (int r = 0; r < rounds; ++r) {
    const int rp = r & 1;
    buf[rp][p][GOFF + sA] = v;           // 1 ds_write_b128, conflict-free
    int na = 2 * r + 2, nb = 2 * r + 3;
    float4 aA2 = angp[na < L ? na : L - 1];
    float4 aB2 = angp[nb < L ? nb : L - 1];
    if (r + 1 < rounds) loadrow(gb, p ? aB2 : aA2, sA, v);   // overlap compute
    __syncthreads();                     // ONE barrier per 2 angles

    accum_angle(&buf[rp][0][0], aA, tiv, tjv, hw, acc);
    if (2 * r + 1 < L)
      accum_angle(&buf[rp][1][0], aB, tiv, tjv, hw, acc);
    aA = aA2; aB = aB2;
  }

  const float scale = (float)(3.14159265358979323846 / (2.0 * (double)L));
#pragma unroll
  for (int k = 0; k < 4; ++k) {
    float* ob = out + (size_t)(n0 + k) * WD * WD + (size_t)(i0 + ty) * WD;
#pragma unroll
    for (int dj = 0; dj < 4; ++dj) {
      float rr = tiv * tiv + tjv[dj] * tjv[dj];
      ob[j0 + tx + 16 * dj] = (rr <= 1.f) ? acc[dj][k] * scale : 0.f;
    }
  }
}

extern "C" void kernel_launch(void* const* d_in, const int* in_sizes, int n_in,
                              void* d_out, int out_size, void* d_ws, size_t ws_size,
                              hipStream_t stream) {
  const float* x = (const float*)d_in[0];
  const float* theta = (const float*)d_in[1];
  float* out = (float*)d_out;
  float* ws = (float*)d_ws;
  int L = in_sizes[1];                       // 512
  int NC = in_sizes[0] / (WD * WD);          // 32
  unsigned char* pk = (unsigned char*)(ws + OFF_PK);

  int nset = LH2 + L;
  hipLaunchKernelGGL(setup_kernel, dim3((nset + 255) / 256), dim3(256), 0, stream,
                     theta, ws, L);
  hipLaunchKernelGGL(filter_kernel, dim3(32, NC), dim3(256), 0, stream,
                     x, ws, pk);
  hipLaunchKernelGGL(backproj_kernel, dim3(64, NC / 4), dim3(1024), 0, stream,
                     ws, pk, out, L);
}